// Round 5
// baseline (2196.568 us; speedup 1.0000x reference)
//
#include <hip/hip_runtime.h>

#define T_SEQ 512
#define HID 256

typedef _Float16 half8 __attribute__((ext_vector_type(8)));
typedef _Float16 half4 __attribute__((ext_vector_type(4)));
typedef float floatx4 __attribute__((ext_vector_type(4)));

// ws layout (in f16 elements). Fragment = 64 lanes x 8 f16 = 512 elems.
#define OFF_GH 0
#define OFF_GI (OFF_GH + 384 * 512)
#define OFF_WB (OFF_GI + 96 * 512)
#define OFF_WD (OFF_WB + 128 * 512)

// gi scratch region (pre-pass output): starts at 4 MB into d_ws.
// size = 64 btiles * 512 t * 8 waves * 6 accs * 64 lanes * 8 B = 805306368 B
#define GI_OFF_BYTES (4ull << 20)
#define GI_T_STRIDE 3072ull          // 8*6*64 uint2 per t
#define GI_B_STRIDE (512ull * 3072ull)
#define WS_NEED (GI_OFF_BYTES + 64ull * GI_B_STRIDE * 8ull)

#define MFMA16(A, B, C) __builtin_amdgcn_mfma_f32_16x16x32_f16(A, B, C, 0, 0, 0)

__device__ __forceinline__ float sigm(float x) { return 1.0f / (1.0f + __expf(-x)); }
__device__ __forceinline__ float tanh_fast(float x) {
  float e = __expf(2.0f * x);
  return 1.0f - 2.0f / (e + 1.0f);
}

// Pack all weights (fp32 in) into f16 MFMA B-fragment order.
__global__ void prep_kernel(const float* __restrict__ w_ih,
                            const float* __restrict__ w_hh,
                            const float* __restrict__ w_base,
                            const float* __restrict__ w_dir,
                            const float* __restrict__ w_mag,
                            _Float16* __restrict__ ws) {
  const int f = blockIdx.x;
  const int lane = threadIdx.x;
  const int col = lane & 15, quad = lane >> 4;
  const float* src;
  int n, k, ld;
  _Float16* dst;
  if (f < 384) {  // w_hh frags: f = (w*8 + kt)*6 + nt ; nt: 0,1=r 2,3=z 4,5=n
    int nt = f % 6, kt = (f / 6) % 8, w = f / 48;
    n = (nt >> 1) * 256 + w * 32 + (nt & 1) * 16 + col;
    k = kt * 32 + quad * 8;
    src = w_hh; ld = 256;
    dst = ws + OFF_GH + ((w * 8 + kt) * 6 + nt) * 512 + lane * 8;
  } else if (f < 480) {  // w_ih frags
    int f2 = f - 384;
    int nt = f2 % 6, kt = (f2 / 6) % 2, w = f2 / 12;
    n = (nt >> 1) * 256 + w * 32 + (nt & 1) * 16 + col;
    k = kt * 32 + quad * 8;
    src = w_ih; ld = 64;
    dst = ws + OFF_GI + ((w * 2 + kt) * 6 + nt) * 512 + lane * 8;
  } else if (f < 608) {  // w_base frags
    int f3 = f - 480;
    int nt = f3 % 2, kt = (f3 / 2) % 8, w = f3 / 16;
    n = w * 32 + nt * 16 + col;
    k = kt * 32 + quad * 8;
    src = w_base; ld = 256;
    dst = ws + OFF_WB + ((w * 8 + kt) * 2 + nt) * 512 + lane * 8;
  } else {  // dir/mag combined: cols 0..7 dir, 8..15 mag
    int kt = f - 608;
    k = kt * 32 + quad * 8;
    ld = 256;
    if (col < 8) { src = w_dir; n = col; } else { src = w_mag; n = col - 8; }
    dst = ws + OFF_WD + kt * 512 + lane * 8;
  }
#pragma unroll
  for (int j = 0; j < 8; ++j)
    dst[j] = (_Float16)src[n * ld + k + j];
}

// Pre-pass: gi[b,t] = x[b,t] @ w_ih^T (+ biases folded in), written f16 in
// the exact per-lane acc layout the main kernel consumes:
//   uint2 @ [btile][t][wave][acc(6)][lane]  (4 f16 = acc rows r2=0..3)
// accs: 0,1 = r(s0,s1)  2,3 = z  4,5 = i_n.  r,z carry b_ih+b_hh; n carries
// b_ih only. 256 blocks (btile x t-quarter) x 512 thr — all CUs, no barriers.
__global__ __launch_bounds__(512, 1)
void gi_prepass_kernel(const float* __restrict__ x_seq,
                       const float* __restrict__ b_ih,
                       const float* __restrict__ b_hh,
                       const _Float16* __restrict__ ws,
                       uint2* __restrict__ gi_out) {
  const int tid = threadIdx.x;
  const int lane = tid & 63;
  const int w = tid >> 6;
  const int col = lane & 15;
  const int quad = lane >> 4;
  const int btile = blockIdx.x >> 2, tq = blockIdx.x & 3;
  const int row0 = btile * 16;

  const half8* __restrict__ gip = (const half8*)(ws + OFF_GI) + w * (12 * 64);
  half8 wg[12];
#pragma unroll
  for (int f = 0; f < 12; ++f) wg[f] = gip[f * 64 + lane];

  float bias[6];
#pragma unroll
  for (int a = 0; a < 6; ++a) {
    const int c = w * 32 + (a & 1) * 16 + col;
    const int g = a >> 1;
    bias[a] = (g < 2) ? (b_ih[g * 256 + c] + b_hh[g * 256 + c]) : b_ih[512 + c];
  }

  const float* const xlane = x_seq + (size_t)(row0 + col) * (T_SEQ * 64) + quad * 8;
  uint2* const gout = gi_out + (size_t)btile * GI_B_STRIDE + (size_t)w * 384 + lane;

  float4 xc[4], xn[4];
  {
    const float* p = xlane + (size_t)(tq * 128) * 64;
    xc[0] = *(const float4*)(p);
    xc[1] = *(const float4*)(p + 4);
    xc[2] = *(const float4*)(p + 32);
    xc[3] = *(const float4*)(p + 36);
  }

#pragma unroll 1
  for (int tt = 0; tt < 128; ++tt) {
    const int t = tq * 128 + tt;
    if (tt + 1 < 128) {
      const float* p = xlane + (size_t)(t + 1) * 64;
      xn[0] = *(const float4*)(p);
      xn[1] = *(const float4*)(p + 4);
      xn[2] = *(const float4*)(p + 32);
      xn[3] = *(const float4*)(p + 36);
    }
    half8 ax0, ax1;
#pragma unroll
    for (int j = 0; j < 4; ++j) {
      ax0[j]     = (_Float16)((const float*)&xc[0])[j];
      ax0[4 + j] = (_Float16)((const float*)&xc[1])[j];
      ax1[j]     = (_Float16)((const float*)&xc[2])[j];
      ax1[4 + j] = (_Float16)((const float*)&xc[3])[j];
    }

    floatx4 acc[6];
#pragma unroll
    for (int a = 0; a < 6; ++a) acc[a] = (floatx4){0.f, 0.f, 0.f, 0.f};
#pragma unroll
    for (int nt = 0; nt < 6; ++nt) {
      acc[nt] = MFMA16(ax0, wg[nt], acc[nt]);
      acc[nt] = MFMA16(ax1, wg[6 + nt], acc[nt]);
    }

    uint2* gp = gout + (size_t)t * GI_T_STRIDE;
#pragma unroll
    for (int a = 0; a < 6; ++a) {
      union { uint2 u; half4 h; } pk;
#pragma unroll
      for (int r2 = 0; r2 < 4; ++r2)
        pk.h[r2] = (_Float16)(acc[a][r2] + bias[a]);
      gp[a * 64] = pk.u;
    }
#pragma unroll
    for (int i = 0; i < 4; ++i) xc[i] = xn[i];
  }
}

// Main sequential kernel: 64 blocks x 512 thr. Per wave-step: 48 MFMAs
// (gh only) into 6 accs; weights 16 frags VGPR-resident + 32 streamed in
// 4x8 batches; gi arrives as 6 coalesced dwordx2 loads consumed only in the
// epilogue. LDS = 16KB h-shadow only. h carried fp32 in registers.
__global__ __launch_bounds__(512, 2)
void gru_main_kernel(const float* __restrict__ b_hh,
                     const float* __restrict__ b_base,
                     const float* __restrict__ b_dir,
                     const float* __restrict__ b_mag,
                     const _Float16* __restrict__ ws,
                     const uint2* __restrict__ gi_in,
                     float* __restrict__ out) {
  __shared__ __align__(16) _Float16 hlin[2][4096];   // [kt(8)][q(4)][row(16)][8]

  const int tid = threadIdx.x;
  const int lane = tid & 63;
  const int w = tid >> 6;
  const int col = lane & 15;
  const int quad = lane >> 4;
  const int row0 = blockIdx.x * 16;

  *(half8*)&hlin[0][tid * 8] = (half8)((_Float16)0.0f);

  float bhn[2];
#pragma unroll
  for (int s = 0; s < 2; ++s) bhn[s] = b_hh[512 + w * 32 + s * 16 + col];

  float hreg[2][4];
#pragma unroll
  for (int s = 0; s < 2; ++s)
#pragma unroll
    for (int r2 = 0; r2 < 4; ++r2) hreg[s][r2] = 0.0f;

  const half8* __restrict__ ghp = (const half8*)(ws + OFF_GH) + w * (48 * 64);
  const half8* __restrict__ wbp = (const half8*)(ws + OFF_WB) + w * (16 * 64);
  const half8* __restrict__ wdp = (const half8*)(ws + OFF_WD);

  half8 wreg[16];
#pragma unroll
  for (int f = 0; f < 16; ++f) wreg[f] = ghp[f * 64 + lane];

  const uint2* const gilane =
      gi_in + (size_t)blockIdx.x * GI_B_STRIDE + (size_t)w * 384 + lane;

#pragma unroll 1
  for (int t = 0; t < T_SEQ; ++t) {
    __syncthreads();
    const int cur = t & 1;
    const _Float16* hc = hlin[cur];
    _Float16* hn = hlin[cur ^ 1];

    // gi loads — consumed only in the epilogue (max latency cover)
    uint2 g[6];
    const uint2* gp = gilane + (size_t)t * GI_T_STRIDE;
#pragma unroll
    for (int a = 0; a < 6; ++a) g[a] = gp[a * 64];

    // stream batches S1,S2 (gh f16..31)
    half8 s1[8], s2[8];
#pragma unroll
    for (int i = 0; i < 8; ++i) s1[i] = ghp[(16 + i) * 64 + lane];
#pragma unroll
    for (int i = 0; i < 8; ++i) s2[i] = ghp[(24 + i) * 64 + lane];

    half8 ah[8];
#pragma unroll
    for (int kt = 0; kt < 8; ++kt)
      ah[kt] = *(const half8*)&hc[kt * 512 + lane * 8];

    floatx4 acc[6];
#pragma unroll
    for (int a = 0; a < 6; ++a) acc[a] = (floatx4){0.f, 0.f, 0.f, 0.f};

    // Phase A: VGPR-resident f0..15 (covers S1/S2)
#pragma unroll
    for (int f = 0; f < 16; ++f)
      acc[f % 6] = MFMA16(ah[f / 6], wreg[f], acc[f % 6]);

    half8 s3[8];
#pragma unroll
    for (int i = 0; i < 8; ++i) s3[i] = ghp[(32 + i) * 64 + lane];

    // Phase B: S1 = f16..23
#pragma unroll
    for (int i = 0; i < 8; ++i) {
      const int f = 16 + i;
      acc[f % 6] = MFMA16(ah[f / 6], s1[i], acc[f % 6]);
    }

    half8 s4[8];
#pragma unroll
    for (int i = 0; i < 8; ++i) s4[i] = ghp[(40 + i) * 64 + lane];

    // Phase C: S2 = f24..31
#pragma unroll
    for (int i = 0; i < 8; ++i) {
      const int f = 24 + i;
      acc[f % 6] = MFMA16(ah[f / 6], s2[i], acc[f % 6]);
    }
    // Phase D: S3 = f32..39
#pragma unroll
    for (int i = 0; i < 8; ++i) {
      const int f = 32 + i;
      acc[f % 6] = MFMA16(ah[f / 6], s3[i], acc[f % 6]);
    }
    // Phase E: S4 = f40..47
#pragma unroll
    for (int i = 0; i < 8; ++i) {
      const int f = 40 + i;
      acc[f % 6] = MFMA16(ah[f / 6], s4[i], acc[f % 6]);
    }

    // epilogue
#pragma unroll
    for (int s = 0; s < 2; ++s) {
      const int inner = s * 16 + col;
      const int widx = w * 512 + (inner >> 3) * 128 + (col & 7);
      union { uint2 u; half4 h; } gr, gz, gn;
      gr.u = g[0 + s]; gz.u = g[2 + s]; gn.u = g[4 + s];
#pragma unroll
      for (int r2 = 0; r2 < 4; ++r2) {
        const float rr = sigm(acc[0 + s][r2] + (float)gr.h[r2]);
        const float zz = sigm(acc[2 + s][r2] + (float)gz.h[r2]);
        const float nn = tanh_fast((float)gn.h[r2] + rr * (acc[4 + s][r2] + bhn[s]));
        const float hnew = zz * hreg[s][r2] + (1.0f - zz) * nn;
        hreg[s][r2] = hnew;
        hn[widx + (quad * 4 + r2) * 8] = (_Float16)hnew;
      }
    }
  }

  __syncthreads();
  // head: base = relu(hT @ w_base^T + b_base); h_T in hlin[0]
  {
    floatx4 ab[2];
    ab[0] = (floatx4){0.f, 0.f, 0.f, 0.f};
    ab[1] = (floatx4){0.f, 0.f, 0.f, 0.f};
#pragma unroll
    for (int kt = 0; kt < 8; ++kt) {
      const half8 ahh = *(const half8*)&hlin[0][kt * 512 + lane * 8];
      const half8* bp = wbp + kt * (2 * 64) + lane;
      ab[0] = MFMA16(ahh, bp[0],  ab[0]);
      ab[1] = MFMA16(ahh, bp[64], ab[1]);
    }
#pragma unroll
    for (int s = 0; s < 2; ++s) {
      const int inner = s * 16 + col;
      const int widx = w * 512 + (inner >> 3) * 128 + (col & 7);
      const float bb = b_base[w * 32 + inner];
#pragma unroll
      for (int r2 = 0; r2 < 4; ++r2) {
        const float v = ab[s][r2] + bb;
        hlin[1][widx + (quad * 4 + r2) * 8] = (_Float16)fmaxf(v, 0.0f);
      }
    }
  }
  __syncthreads();

  if (w == 0) {
    floatx4 ad = (floatx4){0.f, 0.f, 0.f, 0.f};
#pragma unroll
    for (int kt = 0; kt < 8; ++kt) {
      const half8 ahh = *(const half8*)&hlin[1][kt * 512 + lane * 8];
      ad = MFMA16(ahh, wdp[kt * 64 + lane], ad);
    }
    const float bd = (col < 8) ? b_dir[col] : b_mag[col - 8];
#pragma unroll
    for (int r2 = 0; r2 < 4; ++r2) {
      const float v = ad[r2] + bd;
      const float act = (col < 8) ? tanh_fast(v) : sigm(v);
      const float other = __shfl_xor(act, 8, 64);
      if (col < 8)
        out[(size_t)(row0 + quad * 4 + r2) * 8 + col] = act * other;
    }
  }
}

// ---------- fallback (R4 kernel, used when ws_size can't hold gi) ----------
__global__ __launch_bounds__(512, 2)
void gru_head_fallback(const float* __restrict__ x_seq,
                       const float* __restrict__ b_ih,
                       const float* __restrict__ b_hh,
                       const float* __restrict__ b_base,
                       const float* __restrict__ b_dir,
                       const float* __restrict__ b_mag,
                       const _Float16* __restrict__ ws,
                       float* __restrict__ out) {
  __shared__ __align__(16) _Float16 hlin[2][4096];
  __shared__ __align__(16) _Float16 wlds[8][4096];

  const int tid = threadIdx.x;
  const int lane = tid & 63;
  const int w = tid >> 6;
  const int col = lane & 15;
  const int quad = lane >> 4;
  const int row0 = blockIdx.x * 16;

  *(half8*)&hlin[0][tid * 8] = (half8)((_Float16)0.0f);

  float br[2], bz[2], bin_[2], bhn[2];
#pragma unroll
  for (int s = 0; s < 2; ++s) {
    const int c = w * 32 + s * 16 + col;
    br[s] = b_ih[c] + b_hh[c];
    bz[s] = b_ih[256 + c] + b_hh[256 + c];
    bin_[s] = b_ih[512 + c];
    bhn[s] = b_hh[512 + c];
  }
  float hreg[2][4];
#pragma unroll
  for (int s = 0; s < 2; ++s)
#pragma unroll
    for (int r2 = 0; r2 < 4; ++r2) hreg[s][r2] = 0.0f;

  const half8* __restrict__ ghp = (const half8*)(ws + OFF_GH) + w * (48 * 64);
  const half8* __restrict__ gip = (const half8*)(ws + OFF_GI) + w * (12 * 64);
  const half8* __restrict__ wbp = (const half8*)(ws + OFF_WB) + w * (16 * 64);
  const half8* __restrict__ wdp = (const half8*)(ws + OFF_WD);

  half8 wreg[16];
#pragma unroll
  for (int f = 0; f < 16; ++f) wreg[f] = ghp[f * 64 + lane];
  _Float16* const wlw = wlds[w];
#pragma unroll
  for (int j = 0; j < 8; ++j)
    *(half8*)&wlw[j * 512 + lane * 8] = ghp[(16 + j) * 64 + lane];

  const float* const xlane = x_seq + ((size_t)(row0 + col) * T_SEQ) * 64 + quad * 8;
  float4 xc[4], xn[4];
  {
    const float* p = xlane;
    xc[0] = *(const float4*)(p);
    xc[1] = *(const float4*)(p + 4);
    xc[2] = *(const float4*)(p + 32);
    xc[3] = *(const float4*)(p + 36);
  }

  auto body = [&](int t, int tpre, int cur, float4* xcur, float4* xnext) {
    const int nxt = cur ^ 1;
    __syncthreads();
    half8 s1[6], s2[6];
#pragma unroll
    for (int i = 0; i < 6; ++i) s1[i] = ghp[(24 + i) * 64 + lane];
#pragma unroll
    for (int i = 0; i < 6; ++i) s2[i] = ghp[(30 + i) * 64 + lane];
    {
      const float* p = xlane + (size_t)tpre * 64;
      xnext[0] = *(const float4*)(p);
      xnext[1] = *(const float4*)(p + 4);
      xnext[2] = *(const float4*)(p + 32);
      xnext[3] = *(const float4*)(p + 36);
    }
    half8 ah[8];
#pragma unroll
    for (int kt = 0; kt < 8; ++kt)
      ah[kt] = *(const half8*)&hlin[cur][kt * 512 + lane * 8];
    half8 wl[8];
#pragma unroll
    for (int j = 0; j < 8; ++j)
      wl[j] = *(const half8*)&wlw[j * 512 + lane * 8];
    half8 ax0, ax1;
#pragma unroll
    for (int j = 0; j < 4; ++j) {
      ax0[j]     = (_Float16)((const float*)&xcur[0])[j];
      ax0[4 + j] = (_Float16)((const float*)&xcur[1])[j];
      ax1[j]     = (_Float16)((const float*)&xcur[2])[j];
      ax1[4 + j] = (_Float16)((const float*)&xcur[3])[j];
    }
    floatx4 acc[8];
#pragma unroll
    for (int i = 0; i < 8; ++i) acc[i] = (floatx4){0.f, 0.f, 0.f, 0.f};
#pragma unroll
    for (int f = 0; f < 16; ++f)
      acc[f % 6] = MFMA16(ah[f / 6], wreg[f], acc[f % 6]);
    half8 s3[6];
#pragma unroll
    for (int i = 0; i < 6; ++i) s3[i] = ghp[(36 + i) * 64 + lane];
#pragma unroll
    for (int j = 0; j < 8; ++j) {
      const int f = 16 + j;
      acc[f % 6] = MFMA16(ah[f / 6], wl[j], acc[f % 6]);
    }
#pragma unroll
    for (int i = 0; i < 6; ++i) {
      const int f = 24 + i;
      acc[f % 6] = MFMA16(ah[f / 6], s1[i], acc[f % 6]);
    }
    half8 s4[6];
#pragma unroll
    for (int i = 0; i < 6; ++i) s4[i] = ghp[(42 + i) * 64 + lane];
#pragma unroll
    for (int i = 0; i < 6; ++i) {
      const int f = 30 + i;
      acc[f % 6] = MFMA16(ah[f / 6], s2[i], acc[f % 6]);
    }
    half8 s5[6];
#pragma unroll
    for (int i = 0; i < 6; ++i) s5[i] = gip[i * 64 + lane];
#pragma unroll
    for (int i = 0; i < 6; ++i) {
      const int f = 36 + i;
      acc[f % 6] = MFMA16(ah[f / 6], s3[i], acc[f % 6]);
    }
    half8 s6[6];
#pragma unroll
    for (int i = 0; i < 6; ++i) s6[i] = gip[(6 + i) * 64 + lane];
#pragma unroll
    for (int i = 0; i < 6; ++i) {
      const int f = 42 + i;
      acc[f % 6] = MFMA16(ah[f / 6], s4[i], acc[f % 6]);
    }
#pragma unroll
    for (int i = 0; i < 6; ++i) {
      const int aidx = (i < 4) ? i : i + 2;
      acc[aidx] = MFMA16(ax0, s5[i], acc[aidx]);
    }
#pragma unroll
    for (int i = 0; i < 6; ++i) {
      const int aidx = (i < 4) ? i : i + 2;
      acc[aidx] = MFMA16(ax1, s6[i], acc[aidx]);
    }
#pragma unroll
    for (int s = 0; s < 2; ++s) {
      const int inner = s * 16 + col;
      const int widx = w * 512 + (inner >> 3) * 128 + (col & 7);
#pragma unroll
      for (int r2 = 0; r2 < 4; ++r2) {
        const float rr = sigm(acc[0 + s][r2] + br[s]);
        const float zz = sigm(acc[2 + s][r2] + bz[s]);
        const float nn = tanh_fast(acc[6 + s][r2] + bin_[s] + rr * (acc[4 + s][r2] + bhn[s]));
        const float hnew = zz * hreg[s][r2] + (1.0f - zz) * nn;
        hreg[s][r2] = hnew;
        hlin[nxt][widx + (quad * 4 + r2) * 8] = (_Float16)hnew;
      }
    }
  };

#pragma unroll 1
  for (int t = 0; t < T_SEQ; t += 2) {
    body(t, t + 1, 0, xc, xn);
    const int tp2 = (t + 2 < T_SEQ) ? (t + 2) : (T_SEQ - 1);
    body(t + 1, tp2, 1, xn, xc);
  }

  __syncthreads();
  {
    floatx4 ab[2];
    ab[0] = (floatx4){0.f, 0.f, 0.f, 0.f};
    ab[1] = (floatx4){0.f, 0.f, 0.f, 0.f};
#pragma unroll
    for (int kt = 0; kt < 8; ++kt) {
      const half8 ahh = *(const half8*)&hlin[0][kt * 512 + lane * 8];
      const half8* bp = wbp + kt * (2 * 64) + lane;
      ab[0] = MFMA16(ahh, bp[0],  ab[0]);
      ab[1] = MFMA16(ahh, bp[64], ab[1]);
    }
#pragma unroll
    for (int s = 0; s < 2; ++s) {
      const int inner = s * 16 + col;
      const int widx = w * 512 + (inner >> 3) * 128 + (col & 7);
      const float bb = b_base[w * 32 + inner];
#pragma unroll
      for (int r2 = 0; r2 < 4; ++r2) {
        const float v = ab[s][r2] + bb;
        hlin[1][widx + (quad * 4 + r2) * 8] = (_Float16)fmaxf(v, 0.0f);
      }
    }
  }
  __syncthreads();
  if (w == 0) {
    floatx4 ad = (floatx4){0.f, 0.f, 0.f, 0.f};
#pragma unroll
    for (int kt = 0; kt < 8; ++kt) {
      const half8 ahh = *(const half8*)&hlin[1][kt * 512 + lane * 8];
      ad = MFMA16(ahh, wdp[kt * 64 + lane], ad);
    }
    const float bd = (col < 8) ? b_dir[col] : b_mag[col - 8];
#pragma unroll
    for (int r2 = 0; r2 < 4; ++r2) {
      const float v = ad[r2] + bd;
      const float act = (col < 8) ? tanh_fast(v) : sigm(v);
      const float other = __shfl_xor(act, 8, 64);
      if (col < 8)
        out[(size_t)(row0 + quad * 4 + r2) * 8 + col] = act * other;
    }
  }
}

extern "C" void kernel_launch(void* const* d_in, const int* in_sizes, int n_in,
                              void* d_out, int out_size, void* d_ws, size_t ws_size,
                              hipStream_t stream) {
  const float* x_seq  = (const float*)d_in[0];
  const float* b_ih   = (const float*)d_in[3];
  const float* b_hh   = (const float*)d_in[4];
  const float* b_base = (const float*)d_in[6];
  const float* b_dir  = (const float*)d_in[8];
  const float* b_mag  = (const float*)d_in[10];
  _Float16* ws = (_Float16*)d_ws;
  float* out = (float*)d_out;

  hipLaunchKernelGGL(prep_kernel, dim3(616), dim3(64), 0, stream,
                     (const float*)d_in[1], (const float*)d_in[2],
                     (const float*)d_in[5], (const float*)d_in[7],
                     (const float*)d_in[9], ws);

  if (ws_size >= WS_NEED) {
    uint2* gi = (uint2*)((char*)d_ws + GI_OFF_BYTES);
    hipLaunchKernelGGL(gi_prepass_kernel, dim3(256), dim3(512), 0, stream,
                       x_seq, b_ih, b_hh, ws, gi);
    hipLaunchKernelGGL(gru_main_kernel, dim3(64), dim3(512), 0, stream,
                       b_hh, b_base, b_dir, b_mag, ws, gi, out);
  } else {
    hipLaunchKernelGGL(gru_head_fallback, dim3(64), dim3(512), 0, stream,
                       x_seq, b_ih, b_hh, b_base, b_dir, b_mag, ws, out);
  }
}

// Round 6
// 1915.206 us; speedup vs baseline: 1.1469x; 1.1469x over previous
//
#include <hip/hip_runtime.h>

#define T_SEQ 512
#define HID 256

typedef _Float16 half8 __attribute__((ext_vector_type(8)));
typedef _Float16 half4 __attribute__((ext_vector_type(4)));
typedef float floatx4 __attribute__((ext_vector_type(4)));

// ws layout: [0,4MB) weight frags (f16) ; [4MB,5MB) hsave fp32 ; [6MB,...) gi
#define OFF_GH 0
#define OFF_GI (OFF_GH + 384 * 512)
#define OFF_WB (OFF_GI + 96 * 512)
#define OFF_WD (OFF_WB + 128 * 512)
#define HSAVE_OFF_BYTES (4ull << 20)
#define GI_OFF_BYTES (6ull << 20)

#define MFMA16(A, B, C) __builtin_amdgcn_mfma_f32_16x16x32_f16(A, B, C, 0, 0, 0)

__device__ __forceinline__ float sigm(float x) { return 1.0f / (1.0f + __expf(-x)); }
__device__ __forceinline__ float tanh_fast(float x) {
  float e = __expf(2.0f * x);
  return 1.0f - 2.0f / (e + 1.0f);
}

// Pack all weights (fp32 in) into f16 MFMA B-fragment order.
__global__ void prep_kernel(const float* __restrict__ w_ih,
                            const float* __restrict__ w_hh,
                            const float* __restrict__ w_base,
                            const float* __restrict__ w_dir,
                            const float* __restrict__ w_mag,
                            _Float16* __restrict__ ws) {
  const int f = blockIdx.x;
  const int lane = threadIdx.x;
  const int col = lane & 15, quad = lane >> 4;
  const float* src;
  int n, k, ld;
  _Float16* dst;
  if (f < 384) {  // w_hh frags: f = (w*8 + kt)*6 + nt ; nt: 0,1=r 2,3=z 4,5=n
    int nt = f % 6, kt = (f / 6) % 8, w = f / 48;
    n = (nt >> 1) * 256 + w * 32 + (nt & 1) * 16 + col;
    k = kt * 32 + quad * 8;
    src = w_hh; ld = 256;
    dst = ws + OFF_GH + ((w * 8 + kt) * 6 + nt) * 512 + lane * 8;
  } else if (f < 480) {  // w_ih frags
    int f2 = f - 384;
    int nt = f2 % 6, kt = (f2 / 6) % 2, w = f2 / 12;
    n = (nt >> 1) * 256 + w * 32 + (nt & 1) * 16 + col;
    k = kt * 32 + quad * 8;
    src = w_ih; ld = 64;
    dst = ws + OFF_GI + ((w * 2 + kt) * 6 + nt) * 512 + lane * 8;
  } else if (f < 608) {  // w_base frags
    int f3 = f - 480;
    int nt = f3 % 2, kt = (f3 / 2) % 8, w = f3 / 16;
    n = w * 32 + nt * 16 + col;
    k = kt * 32 + quad * 8;
    src = w_base; ld = 256;
    dst = ws + OFF_WB + ((w * 8 + kt) * 2 + nt) * 512 + lane * 8;
  } else {  // dir/mag combined: cols 0..7 dir, 8..15 mag
    int kt = f - 608;
    k = kt * 32 + quad * 8;
    ld = 256;
    if (col < 8) { src = w_dir; n = col; } else { src = w_mag; n = col - 8; }
    dst = ws + OFF_WD + kt * 512 + lane * 8;
  }
#pragma unroll
  for (int j = 0; j < 8; ++j)
    dst[j] = (_Float16)src[n * ld + k + j];
}

// Chunked pre-pass: gi[b,t] for t in [t0, t0+chunk), biases folded, f16,
// per-lane acc layout: uint2 @ [btile][t_local][wave][acc(6)][lane].
// Grid = 64 btiles * nTq, each block does 32 steps for 16 batch rows.
__global__ __launch_bounds__(512, 1)
void gi_prepass_kernel(const float* __restrict__ x_seq,
                       const float* __restrict__ b_ih,
                       const float* __restrict__ b_hh,
                       const _Float16* __restrict__ ws,
                       uint2* __restrict__ gi_out,
                       int t0, int nTq, int chunk) {
  const int tid = threadIdx.x;
  const int lane = tid & 63;
  const int w = tid >> 6;
  const int col = lane & 15;
  const int quad = lane >> 4;
  const int btile = blockIdx.x / nTq, tq = blockIdx.x % nTq;
  const int row0 = btile * 16;
  const int tstart = t0 + tq * 32;

  const half8* __restrict__ gip = (const half8*)(ws + OFF_GI) + w * (12 * 64);
  half8 wg[12];
#pragma unroll
  for (int f = 0; f < 12; ++f) wg[f] = gip[f * 64 + lane];

  float bias[6];
#pragma unroll
  for (int a = 0; a < 6; ++a) {
    const int c = w * 32 + (a & 1) * 16 + col;
    const int g = a >> 1;
    bias[a] = (g < 2) ? (b_ih[g * 256 + c] + b_hh[g * 256 + c]) : b_ih[512 + c];
  }

  const float* const xlane = x_seq + (size_t)(row0 + col) * (T_SEQ * 64) + quad * 8;
  uint2* const gout = gi_out + (size_t)btile * ((size_t)chunk * 3072) +
                      (size_t)w * 384 + lane;

  float4 xc[4], xn[4];
  {
    const float* p = xlane + (size_t)tstart * 64;
    xc[0] = *(const float4*)(p);
    xc[1] = *(const float4*)(p + 4);
    xc[2] = *(const float4*)(p + 32);
    xc[3] = *(const float4*)(p + 36);
  }

#pragma unroll 1
  for (int tt = 0; tt < 32; ++tt) {
    const int t = tstart + tt;
    if (tt + 1 < 32) {
      const float* p = xlane + (size_t)(t + 1) * 64;
      xn[0] = *(const float4*)(p);
      xn[1] = *(const float4*)(p + 4);
      xn[2] = *(const float4*)(p + 32);
      xn[3] = *(const float4*)(p + 36);
    }
    half8 ax0, ax1;
#pragma unroll
    for (int j = 0; j < 4; ++j) {
      ax0[j]     = (_Float16)((const float*)&xc[0])[j];
      ax0[4 + j] = (_Float16)((const float*)&xc[1])[j];
      ax1[j]     = (_Float16)((const float*)&xc[2])[j];
      ax1[4 + j] = (_Float16)((const float*)&xc[3])[j];
    }

    floatx4 acc[6];
#pragma unroll
    for (int a = 0; a < 6; ++a) acc[a] = (floatx4){0.f, 0.f, 0.f, 0.f};
#pragma unroll
    for (int nt = 0; nt < 6; ++nt) {
      acc[nt] = MFMA16(ax0, wg[nt], acc[nt]);
      acc[nt] = MFMA16(ax1, wg[6 + nt], acc[nt]);
    }

    uint2* gp = gout + (size_t)(t - t0) * 3072;
#pragma unroll
    for (int a = 0; a < 6; ++a) {
      union { uint2 u; half4 h; } pk;
#pragma unroll
      for (int r2 = 0; r2 < 4; ++r2)
        pk.h[r2] = (_Float16)(acc[a][r2] + bias[a]);
      gp[a * 64] = pk.u;
    }
#pragma unroll
    for (int i = 0; i < 4; ++i) xc[i] = xn[i];
  }
}

// Main sequential kernel (one chunk): 64 blocks x 512 thr, 1 block/CU,
// launch_bounds(512,1) so the allocator can keep 40/48 gh weight frags
// VGPR-resident (no spills); 8 frags streamed from L2 per step; gi = 6
// coalesced dwordx2 consumed only in the epilogue. h carried fp32 in
// registers, persisted to ws between chunk launches; f16 shadow in LDS.
__global__ __launch_bounds__(512, 1)
void gru_main_kernel(const float* __restrict__ b_hh,
                     const float* __restrict__ b_base,
                     const float* __restrict__ b_dir,
                     const float* __restrict__ b_mag,
                     const _Float16* __restrict__ ws,
                     const uint2* __restrict__ gi_in,
                     float* __restrict__ hsave,
                     float* __restrict__ out,
                     int chunk, int first, int last) {
  __shared__ __align__(16) _Float16 hlin[2][4096];   // [kt(8)][q(4)][row(16)][8]

  const int tid = threadIdx.x;
  const int lane = tid & 63;
  const int w = tid >> 6;
  const int col = lane & 15;
  const int quad = lane >> 4;
  const int row0 = blockIdx.x * 16;

  float bhn[2];
#pragma unroll
  for (int s = 0; s < 2; ++s) bhn[s] = b_hh[512 + w * 32 + s * 16 + col];

  float hreg[2][4];
  if (first) {
#pragma unroll
    for (int s = 0; s < 2; ++s)
#pragma unroll
      for (int r2 = 0; r2 < 4; ++r2) hreg[s][r2] = 0.0f;
    *(half8*)&hlin[0][tid * 8] = (half8)((_Float16)0.0f);
  } else {
    const float* hp = hsave + ((size_t)blockIdx.x * 512 + tid) * 8;
#pragma unroll
    for (int s = 0; s < 2; ++s) {
      const int inner = s * 16 + col;
      const int widx = w * 512 + (inner >> 3) * 128 + (col & 7);
#pragma unroll
      for (int r2 = 0; r2 < 4; ++r2) {
        hreg[s][r2] = hp[s * 4 + r2];
        hlin[0][widx + (quad * 4 + r2) * 8] = (_Float16)hreg[s][r2];
      }
    }
  }

  const half8* __restrict__ ghp = (const half8*)(ws + OFF_GH) + w * (48 * 64);
  const half8* __restrict__ wbp = (const half8*)(ws + OFF_WB) + w * (16 * 64);
  const half8* __restrict__ wdp = (const half8*)(ws + OFF_WD);

  // VGPR-resident weights: gh frags f0..39
  half8 wreg[40];
#pragma unroll
  for (int f = 0; f < 40; ++f) wreg[f] = ghp[f * 64 + lane];

  const uint2* const gilane =
      gi_in + (size_t)blockIdx.x * ((size_t)chunk * 3072) + (size_t)w * 384 + lane;

#pragma unroll 1
  for (int tl = 0; tl < chunk; ++tl) {
    __syncthreads();
    const int cur = tl & 1;
    const _Float16* hc = hlin[cur];
    _Float16* hn = hlin[cur ^ 1];

    // gi loads — consumed only in the epilogue
    uint2 g[6];
    const uint2* gp = gilane + (size_t)tl * 3072;
#pragma unroll
    for (int a = 0; a < 6; ++a) g[a] = gp[a * 64];

    // streamed weights f40..47 (L2-resident, consumed after resident MFMAs)
    half8 st[8];
#pragma unroll
    for (int i = 0; i < 8; ++i) st[i] = ghp[(40 + i) * 64 + lane];

    half8 ah[8];
#pragma unroll
    for (int kt = 0; kt < 8; ++kt)
      ah[kt] = *(const half8*)&hc[kt * 512 + lane * 8];

    floatx4 acc[6];
#pragma unroll
    for (int a = 0; a < 6; ++a) acc[a] = (floatx4){0.f, 0.f, 0.f, 0.f};

    // resident MFMAs f0..39 (covers the stream + gi latency)
#pragma unroll
    for (int f = 0; f < 40; ++f)
      acc[f % 6] = MFMA16(ah[f / 6], wreg[f], acc[f % 6]);
    // streamed f40..47
#pragma unroll
    for (int i = 0; i < 8; ++i) {
      const int f = 40 + i;
      acc[f % 6] = MFMA16(ah[f / 6], st[i], acc[f % 6]);
    }

    // epilogue
#pragma unroll
    for (int s = 0; s < 2; ++s) {
      const int inner = s * 16 + col;
      const int widx = w * 512 + (inner >> 3) * 128 + (col & 7);
      union { uint2 u; half4 h; } gr, gz, gn;
      gr.u = g[0 + s]; gz.u = g[2 + s]; gn.u = g[4 + s];
#pragma unroll
      for (int r2 = 0; r2 < 4; ++r2) {
        const float rr = sigm(acc[0 + s][r2] + (float)gr.h[r2]);
        const float zz = sigm(acc[2 + s][r2] + (float)gz.h[r2]);
        const float nn = tanh_fast((float)gn.h[r2] + rr * (acc[4 + s][r2] + bhn[s]));
        const float hnew = zz * hreg[s][r2] + (1.0f - zz) * nn;
        hreg[s][r2] = hnew;
        hn[widx + (quad * 4 + r2) * 8] = (_Float16)hnew;
      }
    }
  }

  if (!last) {
    float* hp = hsave + ((size_t)blockIdx.x * 512 + tid) * 8;
#pragma unroll
    for (int s = 0; s < 2; ++s)
#pragma unroll
      for (int r2 = 0; r2 < 4; ++r2) hp[s * 4 + r2] = hreg[s][r2];
    return;
  }

  __syncthreads();
  // head: base = relu(hT @ w_base^T + b_base); h_T in hlin[0] (chunk even)
  {
    floatx4 ab[2];
    ab[0] = (floatx4){0.f, 0.f, 0.f, 0.f};
    ab[1] = (floatx4){0.f, 0.f, 0.f, 0.f};
#pragma unroll
    for (int kt = 0; kt < 8; ++kt) {
      const half8 ahh = *(const half8*)&hlin[0][kt * 512 + lane * 8];
      const half8* bp = wbp + kt * (2 * 64) + lane;
      ab[0] = MFMA16(ahh, bp[0],  ab[0]);
      ab[1] = MFMA16(ahh, bp[64], ab[1]);
    }
#pragma unroll
    for (int s = 0; s < 2; ++s) {
      const int inner = s * 16 + col;
      const int widx = w * 512 + (inner >> 3) * 128 + (col & 7);
      const float bb = b_base[w * 32 + inner];
#pragma unroll
      for (int r2 = 0; r2 < 4; ++r2) {
        const float v = ab[s][r2] + bb;
        hlin[1][widx + (quad * 4 + r2) * 8] = (_Float16)fmaxf(v, 0.0f);
      }
    }
  }
  __syncthreads();

  if (w == 0) {
    floatx4 ad = (floatx4){0.f, 0.f, 0.f, 0.f};
#pragma unroll
    for (int kt = 0; kt < 8; ++kt) {
      const half8 ahh = *(const half8*)&hlin[1][kt * 512 + lane * 8];
      ad = MFMA16(ahh, wdp[kt * 64 + lane], ad);
    }
    const float bd = (col < 8) ? b_dir[col] : b_mag[col - 8];
#pragma unroll
    for (int r2 = 0; r2 < 4; ++r2) {
      const float v = ad[r2] + bd;
      const float act = (col < 8) ? tanh_fast(v) : sigm(v);
      const float other = __shfl_xor(act, 8, 64);
      if (col < 8)
        out[(size_t)(row0 + quad * 4 + r2) * 8 + col] = act * other;
    }
  }
}

// ---------- fallback (R4 kernel, used when ws_size is tiny) ----------
__global__ __launch_bounds__(512, 2)
void gru_head_fallback(const float* __restrict__ x_seq,
                       const float* __restrict__ b_ih,
                       const float* __restrict__ b_hh,
                       const float* __restrict__ b_base,
                       const float* __restrict__ b_dir,
                       const float* __restrict__ b_mag,
                       const _Float16* __restrict__ ws,
                       float* __restrict__ out) {
  __shared__ __align__(16) _Float16 hlin[2][4096];
  __shared__ __align__(16) _Float16 wlds[8][4096];

  const int tid = threadIdx.x;
  const int lane = tid & 63;
  const int w = tid >> 6;
  const int col = lane & 15;
  const int quad = lane >> 4;
  const int row0 = blockIdx.x * 16;

  *(half8*)&hlin[0][tid * 8] = (half8)((_Float16)0.0f);

  float br[2], bz[2], bin_[2], bhn[2];
#pragma unroll
  for (int s = 0; s < 2; ++s) {
    const int c = w * 32 + s * 16 + col;
    br[s] = b_ih[c] + b_hh[c];
    bz[s] = b_ih[256 + c] + b_hh[256 + c];
    bin_[s] = b_ih[512 + c];
    bhn[s] = b_hh[512 + c];
  }
  float hreg[2][4];
#pragma unroll
  for (int s = 0; s < 2; ++s)
#pragma unroll
    for (int r2 = 0; r2 < 4; ++r2) hreg[s][r2] = 0.0f;

  const half8* __restrict__ ghp = (const half8*)(ws + OFF_GH) + w * (48 * 64);
  const half8* __restrict__ gip = (const half8*)(ws + OFF_GI) + w * (12 * 64);
  const half8* __restrict__ wbp = (const half8*)(ws + OFF_WB) + w * (16 * 64);
  const half8* __restrict__ wdp = (const half8*)(ws + OFF_WD);

  half8 wreg[16];
#pragma unroll
  for (int f = 0; f < 16; ++f) wreg[f] = ghp[f * 64 + lane];
  _Float16* const wlw = wlds[w];
#pragma unroll
  for (int j = 0; j < 8; ++j)
    *(half8*)&wlw[j * 512 + lane * 8] = ghp[(16 + j) * 64 + lane];

  const float* const xlane = x_seq + ((size_t)(row0 + col) * T_SEQ) * 64 + quad * 8;
  float4 xc[4], xn[4];
  {
    const float* p = xlane;
    xc[0] = *(const float4*)(p);
    xc[1] = *(const float4*)(p + 4);
    xc[2] = *(const float4*)(p + 32);
    xc[3] = *(const float4*)(p + 36);
  }

  auto body = [&](int t, int tpre, int cur, float4* xcur, float4* xnext) {
    const int nxt = cur ^ 1;
    __syncthreads();
    half8 s1[6], s2[6];
#pragma unroll
    for (int i = 0; i < 6; ++i) s1[i] = ghp[(24 + i) * 64 + lane];
#pragma unroll
    for (int i = 0; i < 6; ++i) s2[i] = ghp[(30 + i) * 64 + lane];
    {
      const float* p = xlane + (size_t)tpre * 64;
      xnext[0] = *(const float4*)(p);
      xnext[1] = *(const float4*)(p + 4);
      xnext[2] = *(const float4*)(p + 32);
      xnext[3] = *(const float4*)(p + 36);
    }
    half8 ah[8];
#pragma unroll
    for (int kt = 0; kt < 8; ++kt)
      ah[kt] = *(const half8*)&hlin[cur][kt * 512 + lane * 8];
    half8 wl[8];
#pragma unroll
    for (int j = 0; j < 8; ++j)
      wl[j] = *(const half8*)&wlw[j * 512 + lane * 8];
    half8 ax0, ax1;
#pragma unroll
    for (int j = 0; j < 4; ++j) {
      ax0[j]     = (_Float16)((const float*)&xcur[0])[j];
      ax0[4 + j] = (_Float16)((const float*)&xcur[1])[j];
      ax1[j]     = (_Float16)((const float*)&xcur[2])[j];
      ax1[4 + j] = (_Float16)((const float*)&xcur[3])[j];
    }
    floatx4 acc[8];
#pragma unroll
    for (int i = 0; i < 8; ++i) acc[i] = (floatx4){0.f, 0.f, 0.f, 0.f};
#pragma unroll
    for (int f = 0; f < 16; ++f)
      acc[f % 6] = MFMA16(ah[f / 6], wreg[f], acc[f % 6]);
    half8 s3[6];
#pragma unroll
    for (int i = 0; i < 6; ++i) s3[i] = ghp[(36 + i) * 64 + lane];
#pragma unroll
    for (int j = 0; j < 8; ++j) {
      const int f = 16 + j;
      acc[f % 6] = MFMA16(ah[f / 6], wl[j], acc[f % 6]);
    }
#pragma unroll
    for (int i = 0; i < 6; ++i) {
      const int f = 24 + i;
      acc[f % 6] = MFMA16(ah[f / 6], s1[i], acc[f % 6]);
    }
    half8 s4[6];
#pragma unroll
    for (int i = 0; i < 6; ++i) s4[i] = ghp[(42 + i) * 64 + lane];
#pragma unroll
    for (int i = 0; i < 6; ++i) {
      const int f = 30 + i;
      acc[f % 6] = MFMA16(ah[f / 6], s2[i], acc[f % 6]);
    }
    half8 s5[6];
#pragma unroll
    for (int i = 0; i < 6; ++i) s5[i] = gip[i * 64 + lane];
#pragma unroll
    for (int i = 0; i < 6; ++i) {
      const int f = 36 + i;
      acc[f % 6] = MFMA16(ah[f / 6], s3[i], acc[f % 6]);
    }
    half8 s6[6];
#pragma unroll
    for (int i = 0; i < 6; ++i) s6[i] = gip[(6 + i) * 64 + lane];
#pragma unroll
    for (int i = 0; i < 6; ++i) {
      const int f = 42 + i;
      acc[f % 6] = MFMA16(ah[f / 6], s4[i], acc[f % 6]);
    }
#pragma unroll
    for (int i = 0; i < 6; ++i) {
      const int aidx = (i < 4) ? i : i + 2;
      acc[aidx] = MFMA16(ax0, s5[i], acc[aidx]);
    }
#pragma unroll
    for (int i = 0; i < 6; ++i) {
      const int aidx = (i < 4) ? i : i + 2;
      acc[aidx] = MFMA16(ax1, s6[i], acc[aidx]);
    }
#pragma unroll
    for (int s = 0; s < 2; ++s) {
      const int inner = s * 16 + col;
      const int widx = w * 512 + (inner >> 3) * 128 + (col & 7);
#pragma unroll
      for (int r2 = 0; r2 < 4; ++r2) {
        const float rr = sigm(acc[0 + s][r2] + br[s]);
        const float zz = sigm(acc[2 + s][r2] + bz[s]);
        const float nn = tanh_fast(acc[6 + s][r2] + bin_[s] + rr * (acc[4 + s][r2] + bhn[s]));
        const float hnew = zz * hreg[s][r2] + (1.0f - zz) * nn;
        hreg[s][r2] = hnew;
        hlin[nxt][widx + (quad * 4 + r2) * 8] = (_Float16)hnew;
      }
    }
  };

#pragma unroll 1
  for (int t = 0; t < T_SEQ; t += 2) {
    body(t, t + 1, 0, xc, xn);
    const int tp2 = (t + 2 < T_SEQ) ? (t + 2) : (T_SEQ - 1);
    body(t + 1, tp2, 1, xn, xc);
  }

  __syncthreads();
  {
    floatx4 ab[2];
    ab[0] = (floatx4){0.f, 0.f, 0.f, 0.f};
    ab[1] = (floatx4){0.f, 0.f, 0.f, 0.f};
#pragma unroll
    for (int kt = 0; kt < 8; ++kt) {
      const half8 ahh = *(const half8*)&hlin[0][kt * 512 + lane * 8];
      const half8* bp = wbp + kt * (2 * 64) + lane;
      ab[0] = MFMA16(ahh, bp[0],  ab[0]);
      ab[1] = MFMA16(ahh, bp[64], ab[1]);
    }
#pragma unroll
    for (int s = 0; s < 2; ++s) {
      const int inner = s * 16 + col;
      const int widx = w * 512 + (inner >> 3) * 128 + (col & 7);
      const float bb = b_base[w * 32 + inner];
#pragma unroll
      for (int r2 = 0; r2 < 4; ++r2) {
        const float v = ab[s][r2] + bb;
        hlin[1][widx + (quad * 4 + r2) * 8] = (_Float16)fmaxf(v, 0.0f);
      }
    }
  }
  __syncthreads();
  if (w == 0) {
    floatx4 ad = (floatx4){0.f, 0.f, 0.f, 0.f};
#pragma unroll
    for (int kt = 0; kt < 8; ++kt) {
      const half8 ahh = *(const half8*)&hlin[1][kt * 512 + lane * 8];
      ad = MFMA16(ahh, wdp[kt * 64 + lane], ad);
    }
    const float bd = (col < 8) ? b_dir[col] : b_mag[col - 8];
#pragma unroll
    for (int r2 = 0; r2 < 4; ++r2) {
      const float v = ad[r2] + bd;
      const float act = (col < 8) ? tanh_fast(v) : sigm(v);
      const float other = __shfl_xor(act, 8, 64);
      if (col < 8)
        out[(size_t)(row0 + quad * 4 + r2) * 8 + col] = act * other;
    }
  }
}

extern "C" void kernel_launch(void* const* d_in, const int* in_sizes, int n_in,
                              void* d_out, int out_size, void* d_ws, size_t ws_size,
                              hipStream_t stream) {
  const float* x_seq  = (const float*)d_in[0];
  const float* b_ih   = (const float*)d_in[3];
  const float* b_hh   = (const float*)d_in[4];
  const float* b_base = (const float*)d_in[6];
  const float* b_dir  = (const float*)d_in[8];
  const float* b_mag  = (const float*)d_in[10];
  _Float16* ws = (_Float16*)d_ws;
  float* out = (float*)d_out;

  hipLaunchKernelGGL(prep_kernel, dim3(616), dim3(64), 0, stream,
                     (const float*)d_in[1], (const float*)d_in[2],
                     (const float*)d_in[5], (const float*)d_in[7],
                     (const float*)d_in[9], ws);

  // pick largest chunk whose gi buffer fits: bytes = 64 * chunk * 3072 * 8
  int chunk = 0;
  const int cand[3] = {128, 64, 32};
  for (int i = 0; i < 3; ++i) {
    const size_t need = GI_OFF_BYTES + 64ull * (size_t)cand[i] * 3072ull * 8ull;
    if (ws_size >= need) { chunk = cand[i]; break; }
  }

  if (chunk) {
    uint2* gi = (uint2*)((char*)d_ws + GI_OFF_BYTES);
    float* hsave = (float*)((char*)d_ws + HSAVE_OFF_BYTES);
    const int nchunks = T_SEQ / chunk;
    const int nTq = chunk / 32;
    for (int c = 0; c < nchunks; ++c) {
      hipLaunchKernelGGL(gi_prepass_kernel, dim3(64 * nTq), dim3(512), 0, stream,
                         x_seq, b_ih, b_hh, ws, gi, c * chunk, nTq, chunk);
      hipLaunchKernelGGL(gru_main_kernel, dim3(64), dim3(512), 0, stream,
                         b_hh, b_base, b_dir, b_mag, ws, gi, hsave, out,
                         chunk, (c == 0) ? 1 : 0, (c == nchunks - 1) ? 1 : 0);
    }
  } else {
    hipLaunchKernelGGL(gru_head_fallback, dim3(64), dim3(512), 0, stream,
                       x_seq, b_ih, b_hh, b_base, b_dir, b_mag, ws, out);
  }
}